// Round 5
// baseline (574.001 us; speedup 1.0000x reference)
//
#include <hip/hip_runtime.h>
#include <math.h>
#include <stdint.h>

#define ND_ROWS 16384
#define DDIM    256
#define KCODES  8192
#define NSPLIT  8
#define KSEG    (KCODES / NSPLIT)   // 1024

typedef _Float16 f16x4 __attribute__((ext_vector_type(4)));
typedef _Float16 f16x8 __attribute__((ext_vector_type(8)));
typedef float    f32x4 __attribute__((ext_vector_type(4)));

// ---------------------------------------------------------------------------
// ws layout (float offsets):
//   ne        [0,      8192)
//   nx        [8192,   24576)
//   val_part  [24576,  155648)   8 x 16384 floats
//   idx_part  [155648, 286720)   8 x 16384 ints
//   counts    [286720, 294912)   8192 ints   (memset 0 each call)
//   parts     [294912, 303104)   de[4096] | dq[4096] per finalize block
//   Ap        [303104, ...)      16384x512 f16  ([x_hi | x_lo])
//   Bp        Ap + 16384*512     8192x512  f16  ([e_hi | e_lo])
// ---------------------------------------------------------------------------

__device__ __attribute__((always_inline)) inline void load_lds16(const void* g, void* l) {
    __builtin_amdgcn_global_load_lds((const __attribute__((address_space(1))) void*)g,
                                     (__attribute__((address_space(3))) void*)l, 16, 0, 0);
}

// one wave per vector: fp16 hi/lo split + squared-norm
__global__ __launch_bounds__(256) void prep_kernel(const float* __restrict__ x,
                                                   const float* __restrict__ emb,
                                                   _Float16* __restrict__ Ap,
                                                   _Float16* __restrict__ Bp,
                                                   float* __restrict__ nx,
                                                   float* __restrict__ ne) {
    int wave = (blockIdx.x << 2) + (threadIdx.x >> 6);   // [0, 24576)
    int lane = threadIdx.x & 63;
    const float* src;
    _Float16* dst;
    float* dstn;
    if (wave < ND_ROWS) { src = x + (size_t)wave * DDIM; dst = Ap + (size_t)wave * 512; dstn = nx + wave; }
    else { int r = wave - ND_ROWS; src = emb + (size_t)r * DDIM; dst = Bp + (size_t)r * 512; dstn = ne + r; }
    float4 v = ((const float4*)src)[lane];
    f16x4 hi, lo;
    hi[0] = (_Float16)v.x; lo[0] = (_Float16)(v.x - (float)hi[0]);
    hi[1] = (_Float16)v.y; lo[1] = (_Float16)(v.y - (float)hi[1]);
    hi[2] = (_Float16)v.z; lo[2] = (_Float16)(v.z - (float)hi[2]);
    hi[3] = (_Float16)v.w; lo[3] = (_Float16)(v.w - (float)hi[3]);
    *(f16x4*)(dst + lane * 4)       = hi;
    *(f16x4*)(dst + 256 + lane * 4) = lo;
    float s = v.x*v.x + v.y*v.y + v.z*v.z + v.w*v.w;
    #pragma unroll
    for (int m = 32; m; m >>= 1) s += __shfl_xor(s, m, 64);
    if (lane == 0) *dstn = s;
}

// MFMA argmin GEMM, dot = x1.e1 + x1.e2 + x2.e1 (fp16 hi/lo split).
// Unique-chunk staging: per barrier, stage 32 hi-halves + 32 lo-halves of A and B
// (row = 128 B = 8 slots of 16 B), then 3 product passes (hh, hl, lh) = 48 MFMAs.
// Slot swizzle: physical slot = logical ^ (row&7) -> fragment ds_read_b128 is
// 2-way bank-aliased (free); staging fetches the permuted global chunk so
// global_load_lds (wave-uniform base + lane*16) stays legal.
__global__ __launch_bounds__(256, 4) void argmin_mfma(
    const _Float16* __restrict__ Ap, const _Float16* __restrict__ Bp,
    const float* __restrict__ nx, const float* __restrict__ ne,
    float* __restrict__ val_part, int* __restrict__ idx_part) {
    __shared__ __align__(16) _Float16 As[128 * 64];   // [row][hi32|lo32], 16 KB
    __shared__ __align__(16) _Float16 Bs[128 * 64];
    __shared__ float sval2[2][128];
    __shared__ int   sidx2[2][128];

    const int tid  = threadIdx.x;
    const int lane = tid & 63;
    const int w    = tid >> 6;
    const int wx   = w & 1;
    const int wy   = w >> 1;
    const int quad = lane >> 4;
    const int t16  = lane & 15;

    const int ks       = blockIdx.x & 7;    // XCD-affine code split
    const int rt       = blockIdx.x >> 3;
    const int rowBase  = rt * 128;
    const int codeBase = ks * KSEG;

    // staging: per issue j (0..3), lane -> row = w*32 + j*8 + lane/8, physical
    // slot = lane&7; fetch global logical chunk g = (lane&7) ^ ((lane>>3)&7).
    const int srow8  = (w << 5) + (lane >> 3);
    const int g      = (lane & 7) ^ ((lane >> 3) & 7);
    const int goff_h = ((g & 3) << 3) + ((g >> 2) << 8);   // halves: hi/lo select

    float nxr[16];
    #pragma unroll
    for (int mt = 0; mt < 4; ++mt)
        #pragma unroll
        for (int r = 0; r < 4; ++r)
            nxr[mt * 4 + r] = nx[rowBase + wy * 64 + mt * 16 + quad * 4 + r];

    float minval[16];
    int   minidx[16];
    #pragma unroll
    for (int i = 0; i < 16; ++i) { minval[i] = 3.402823466e+38f; minidx[i] = 0; }

    const int sA = quad ^ (t16 & 7);         // hi-frag physical slot (A and B)
    const int sL = (quad ^ 4) ^ (t16 & 7);   // lo-frag physical slot

    for (int jt = 0; jt < KSEG / 128; ++jt) {
        const int colBase = codeBase + jt * 128;
        f32x4 acc[4][4];
        #pragma unroll
        for (int mt = 0; mt < 4; ++mt)
            #pragma unroll
            for (int nt = 0; nt < 4; ++nt) {
                f32x4 z = {0.0f, 0.0f, 0.0f, 0.0f};
                acc[mt][nt] = z;
            }

        for (int kc = 0; kc < 256; kc += 32) {
            __syncthreads();
            #pragma unroll
            for (int j = 0; j < 4; ++j) {
                const char* gA = (const char*)(Ap + (size_t)(rowBase + srow8 + j * 8) * 512 + kc + goff_h);
                load_lds16(gA, (char*)As + (w << 12) + (j << 10));
                const char* gB = (const char*)(Bp + (size_t)(colBase + srow8 + j * 8) * 512 + kc + goff_h);
                load_lds16(gB, (char*)Bs + (w << 12) + (j << 10));
            }
            __syncthreads();

            f16x8 ah[4];
            #pragma unroll
            for (int mt = 0; mt < 4; ++mt) {
                int r = wy * 64 + mt * 16 + t16;
                ah[mt] = *(const f16x8*)((const char*)As + r * 128 + (sA << 4));
            }
            {   // hh + hl: ah live throughout, one B set at a time
                f16x8 bh[4];
                #pragma unroll
                for (int nt = 0; nt < 4; ++nt) {
                    int r = wx * 64 + nt * 16 + t16;
                    bh[nt] = *(const f16x8*)((const char*)Bs + r * 128 + (sA << 4));
                }
                #pragma unroll
                for (int mt = 0; mt < 4; ++mt)
                    #pragma unroll
                    for (int nt = 0; nt < 4; ++nt)
                        acc[mt][nt] = __builtin_amdgcn_mfma_f32_16x16x32_f16(ah[mt], bh[nt], acc[mt][nt], 0, 0, 0);
            }
            {
                f16x8 bl[4];
                #pragma unroll
                for (int nt = 0; nt < 4; ++nt) {
                    int r = wx * 64 + nt * 16 + t16;
                    bl[nt] = *(const f16x8*)((const char*)Bs + r * 128 + (sL << 4));
                }
                #pragma unroll
                for (int mt = 0; mt < 4; ++mt)
                    #pragma unroll
                    for (int nt = 0; nt < 4; ++nt)
                        acc[mt][nt] = __builtin_amdgcn_mfma_f32_16x16x32_f16(ah[mt], bl[nt], acc[mt][nt], 0, 0, 0);
            }
            {   // lh: fresh al, re-read bh (ah/bl dead; peak stays ~2 sets)
                f16x8 al[4], bh2[4];
                #pragma unroll
                for (int mt = 0; mt < 4; ++mt) {
                    int r = wy * 64 + mt * 16 + t16;
                    al[mt] = *(const f16x8*)((const char*)As + r * 128 + (sL << 4));
                }
                #pragma unroll
                for (int nt = 0; nt < 4; ++nt) {
                    int r = wx * 64 + nt * 16 + t16;
                    bh2[nt] = *(const f16x8*)((const char*)Bs + r * 128 + (sA << 4));
                }
                #pragma unroll
                for (int mt = 0; mt < 4; ++mt)
                    #pragma unroll
                    for (int nt = 0; nt < 4; ++nt)
                        acc[mt][nt] = __builtin_amdgcn_mfma_f32_16x16x32_f16(al[mt], bh2[nt], acc[mt][nt], 0, 0, 0);
            }
        }

        #pragma unroll
        for (int nt = 0; nt < 4; ++nt) {
            int col = colBase + wx * 64 + nt * 16 + t16;
            float nec = ne[col];
            #pragma unroll
            for (int mt = 0; mt < 4; ++mt)
                #pragma unroll
                for (int r = 0; r < 4; ++r) {
                    float d = nxr[mt * 4 + r] + nec - 2.0f * acc[mt][nt][r];
                    if (d < minval[mt * 4 + r]) { minval[mt * 4 + r] = d; minidx[mt * 4 + r] = col; }
                }
        }
    }

    // reduce over the 16 col-lanes (lane bits 0-3), tie -> smaller index
    #pragma unroll
    for (int i = 0; i < 16; ++i) {
        float v = minval[i]; int ix = minidx[i];
        #pragma unroll
        for (int m = 1; m < 16; m <<= 1) {
            float ov = __shfl_xor(v, m, 64);
            int   oi = __shfl_xor(ix, m, 64);
            if (ov < v || (ov == v && oi < ix)) { v = ov; ix = oi; }
        }
        minval[i] = v; minidx[i] = ix;
    }
    __syncthreads();
    if (t16 == 0) {
        #pragma unroll
        for (int mt = 0; mt < 4; ++mt)
            #pragma unroll
            for (int r = 0; r < 4; ++r) {
                int rl = wy * 64 + mt * 16 + quad * 4 + r;
                sval2[wx][rl] = minval[mt * 4 + r];
                sidx2[wx][rl] = minidx[mt * 4 + r];
            }
    }
    __syncthreads();
    if (tid < 128) {
        float v0 = sval2[0][tid]; int i0 = sidx2[0][tid];
        float v1 = sval2[1][tid]; int i1 = sidx2[1][tid];
        if (v1 < v0 || (v1 == v0 && i1 < i0)) { v0 = v1; i0 = i1; }
        val_part[ks * ND_ROWS + rowBase + tid] = v0;
        idx_part[ks * ND_ROWS + rowBase + tid] = i0;
    }
}

// merge splits, gather codebook row, write quantized_sg + float index,
// histogram atomic + per-block SSE partials (no same-address float atomics).
__global__ __launch_bounds__(256) void finalize_kernel(
    const float* __restrict__ x, const float* __restrict__ emb,
    const float* __restrict__ val_part, const int* __restrict__ idx_part,
    float* __restrict__ out_q, float* __restrict__ out_idx,
    int* __restrict__ counts, float* __restrict__ parts) {
    __shared__ float rde[4], rdq[4];
    int wv   = threadIdx.x >> 6;
    int row  = (blockIdx.x << 2) + wv;
    int lane = threadIdx.x & 63;

    float bv = val_part[row];
    int   bi = idx_part[row];
    #pragma unroll
    for (int p = 1; p < NSPLIT; ++p) {
        float v  = val_part[p * ND_ROWS + row];
        int   i2 = idx_part[p * ND_ROWS + row];
        if (v < bv || (v == bv && i2 < bi)) { bv = v; bi = i2; }
    }

    float4 xv = ((const float4*)(x   + (size_t)row * DDIM))[lane];
    float4 ev = ((const float4*)(emb + (size_t)bi  * DDIM))[lane];
    float4 q;
    q.x = xv.x + (ev.x - xv.x);
    q.y = xv.y + (ev.y - xv.y);
    q.z = xv.z + (ev.z - xv.z);
    q.w = xv.w + (ev.w - xv.w);
    ((float4*)(out_q + (size_t)row * DDIM))[lane] = q;

    float de = (ev.x - xv.x) * (ev.x - xv.x) + (ev.y - xv.y) * (ev.y - xv.y)
             + (ev.z - xv.z) * (ev.z - xv.z) + (ev.w - xv.w) * (ev.w - xv.w);
    float dq = (q.x - ev.x) * (q.x - ev.x) + (q.y - ev.y) * (q.y - ev.y)
             + (q.z - ev.z) * (q.z - ev.z) + (q.w - ev.w) * (q.w - ev.w);
    #pragma unroll
    for (int m = 32; m; m >>= 1) {
        de += __shfl_xor(de, m, 64);
        dq += __shfl_xor(dq, m, 64);
    }
    if (lane == 0) {
        out_idx[row] = (float)bi;
        atomicAdd(&counts[bi], 1);
        rde[wv] = de; rdq[wv] = dq;
    }
    __syncthreads();
    if (threadIdx.x == 0) {
        parts[blockIdx.x]        = rde[0] + rde[1] + rde[2] + rde[3];
        parts[4096 + blockIdx.x] = rdq[0] + rdq[1] + rdq[2] + rdq[3];
    }
}

__global__ __launch_bounds__(256) void scalars_kernel(
    const int* __restrict__ counts, const float* __restrict__ parts,
    float* __restrict__ out_loss, float* __restrict__ out_perp) {
    __shared__ float red[256], rde[256], rdq[256];
    float local = 0.0f, de = 0.0f, dq = 0.0f;
    for (int k = threadIdx.x; k < KCODES; k += 256) {
        float p = (float)counts[k] * (1.0f / (float)ND_ROWS);
        local += p * logf(p + 1e-10f);
    }
    for (int k = threadIdx.x; k < 4096; k += 256) {
        de += parts[k];
        dq += parts[4096 + k];
    }
    red[threadIdx.x] = local; rde[threadIdx.x] = de; rdq[threadIdx.x] = dq;
    __syncthreads();
    for (int s = 128; s; s >>= 1) {
        if (threadIdx.x < s) {
            red[threadIdx.x] += red[threadIdx.x + s];
            rde[threadIdx.x] += rde[threadIdx.x + s];
            rdq[threadIdx.x] += rdq[threadIdx.x + s];
        }
        __syncthreads();
    }
    if (threadIdx.x == 0) {
        *out_perp = expf(-red[0]);
        float invn = 1.0f / (float)(ND_ROWS * DDIM);
        *out_loss = rdq[0] * invn + 0.25f * (rde[0] * invn);
    }
}

extern "C" void kernel_launch(void* const* d_in, const int* in_sizes, int n_in,
                              void* d_out, int out_size, void* d_ws, size_t ws_size,
                              hipStream_t stream) {
    const float* x   = (const float*)d_in[0];
    const float* emb = (const float*)d_in[1];

    float* ws       = (float*)d_ws;
    float* ne       = ws;
    float* nx       = ws + 8192;
    float* val_part = ws + 24576;
    int*   idx_part = (int*)(ws + 155648);
    int*   counts   = (int*)(ws + 286720);
    float* parts    = ws + 294912;
    _Float16* Ap    = (_Float16*)(ws + 303104);        // 16B-aligned
    _Float16* Bp    = Ap + (size_t)ND_ROWS * 512;

    float* out_q    = (float*)d_out;
    float* out_idx  = out_q + (size_t)ND_ROWS * DDIM;
    float* out_loss = out_idx + ND_ROWS;
    float* out_perp = out_loss + 1;

    hipMemsetAsync(counts, 0, KCODES * sizeof(int), stream);

    prep_kernel<<<(KCODES + ND_ROWS) / 4, 256, 0, stream>>>(x, emb, Ap, Bp, nx, ne);
    argmin_mfma<<<(ND_ROWS / 128) * NSPLIT, 256, 0, stream>>>(Ap, Bp, nx, ne,
                                                              val_part, idx_part);
    finalize_kernel<<<ND_ROWS / 4, 256, 0, stream>>>(x, emb, val_part, idx_part,
                                                     out_q, out_idx, counts, parts);
    scalars_kernel<<<1, 256, 0, stream>>>(counts, parts, out_loss, out_perp);
}

// Round 6
// 338.102 us; speedup vs baseline: 1.6977x; 1.6977x over previous
//
#include <hip/hip_runtime.h>
#include <math.h>
#include <stdint.h>

#define ND_ROWS 16384
#define DDIM    256
#define KCODES  8192
#define NSPLIT  8
#define KSEG    (KCODES / NSPLIT)   // 1024

typedef _Float16 f16x4 __attribute__((ext_vector_type(4)));
typedef _Float16 f16x8 __attribute__((ext_vector_type(8)));
typedef float    f32x4 __attribute__((ext_vector_type(4)));

// ---------------------------------------------------------------------------
// ws layout (float offsets):
//   ne        [0,      8192)
//   nx        [8192,   24576)
//   val_part  [24576,  155648)   8 x 16384 floats
//   idx_part  [155648, 286720)   8 x 16384 ints
//   counts    [286720, 294912)   8192 ints   (memset 0 each call)
//   parts     [294912, 303104)   de[4096] | dq[4096] per finalize block
//   Ap        [303104, ...)      16384x512 f16  ([x_hi | x_lo])
//   Bp        Ap + 16384*512     8192x512  f16  ([e_hi | e_lo])
// ---------------------------------------------------------------------------

__device__ __attribute__((always_inline)) inline void load_lds16(const void* g, void* l) {
    __builtin_amdgcn_global_load_lds((const __attribute__((address_space(1))) void*)g,
                                     (__attribute__((address_space(3))) void*)l, 16, 0, 0);
}

// one wave per vector: fp16 hi/lo split + squared-norm
__global__ __launch_bounds__(256) void prep_kernel(const float* __restrict__ x,
                                                   const float* __restrict__ emb,
                                                   _Float16* __restrict__ Ap,
                                                   _Float16* __restrict__ Bp,
                                                   float* __restrict__ nx,
                                                   float* __restrict__ ne) {
    int wave = (blockIdx.x << 2) + (threadIdx.x >> 6);   // [0, 24576)
    int lane = threadIdx.x & 63;
    const float* src;
    _Float16* dst;
    float* dstn;
    if (wave < ND_ROWS) { src = x + (size_t)wave * DDIM; dst = Ap + (size_t)wave * 512; dstn = nx + wave; }
    else { int r = wave - ND_ROWS; src = emb + (size_t)r * DDIM; dst = Bp + (size_t)r * 512; dstn = ne + r; }
    float4 v = ((const float4*)src)[lane];
    f16x4 hi, lo;
    hi[0] = (_Float16)v.x; lo[0] = (_Float16)(v.x - (float)hi[0]);
    hi[1] = (_Float16)v.y; lo[1] = (_Float16)(v.y - (float)hi[1]);
    hi[2] = (_Float16)v.z; lo[2] = (_Float16)(v.z - (float)hi[2]);
    hi[3] = (_Float16)v.w; lo[3] = (_Float16)(v.w - (float)hi[3]);
    *(f16x4*)(dst + lane * 4)       = hi;
    *(f16x4*)(dst + 256 + lane * 4) = lo;
    float s = v.x*v.x + v.y*v.y + v.z*v.z + v.w*v.w;
    #pragma unroll
    for (int m = 32; m; m >>= 1) s += __shfl_xor(s, m, 64);
    if (lane == 0) *dstn = s;
}

// MFMA argmin GEMM, dot = x1.e1 + x1.e2 + x2.e1 (fp16 hi/lo split).
// Tile = 128 rows x 256 cols per jt (jt=4 -> 1024 codes/block), TM*TN maximized
// to cut staged-issue traffic: A issue = ND*1KB*(K/256) = 512 MB, B issue = 1 GB
// but XCD-resident (ks=blockIdx&7 -> 1 MB segment per XCD L2). 4 waves of 64x128,
// 96 MFMAs per barrier. Slot swizzle: phys slot = logical ^ (row&7) -> fragment
// ds_read_b128 is 2-way bank-aliased (free, measured 0 conflicts in R4/R5).
__global__ __launch_bounds__(256, 2) void argmin_mfma(
    const _Float16* __restrict__ Ap, const _Float16* __restrict__ Bp,
    const float* __restrict__ nx, const float* __restrict__ ne,
    float* __restrict__ val_part, int* __restrict__ idx_part) {
    __shared__ __align__(16) _Float16 As[128 * 64];   // [row][hi32|lo32] = 128 B, 16 KB
    __shared__ __align__(16) _Float16 Bs[256 * 64];   // 32 KB
    __shared__ float sval2[2][128];
    __shared__ int   sidx2[2][128];

    const int tid  = threadIdx.x;
    const int lane = tid & 63;
    const int w    = tid >> 6;
    const int wx   = w & 1;    // col half (128)
    const int wy   = w >> 1;   // row half (64)
    const int quad = lane >> 4;
    const int t16  = lane & 15;

    const int ks       = blockIdx.x & 7;    // XCD-affine code split
    const int rt       = blockIdx.x >> 3;   // 128 row tiles
    const int rowBase  = rt * 128;
    const int codeBase = ks * KSEG;

    // staging: instr (w, j) -> LDS rows [(j*4+w)*8, +8), lane l -> row +l/8,
    // phys slot l&7 holding logical chunk g = (l&7) ^ ((l>>3)&7).
    const int l8    = lane >> 3;             // row-within-8
    const int g     = (lane & 7) ^ (l8 & 7);
    const int goff  = ((g & 3) << 3) + ((g >> 2) << 8);   // f16 offset: hi/lo select

    float nxr[16];
    #pragma unroll
    for (int mt = 0; mt < 4; ++mt)
        #pragma unroll
        for (int r = 0; r < 4; ++r)
            nxr[mt * 4 + r] = nx[rowBase + wy * 64 + mt * 16 + quad * 4 + r];

    float minval[16];
    int   minidx[16];
    #pragma unroll
    for (int i = 0; i < 16; ++i) { minval[i] = 3.402823466e+38f; minidx[i] = 0; }

    const int sA = quad ^ (t16 & 7);         // hi-frag phys slot
    const int sL = (quad ^ 4) ^ (t16 & 7);   // lo-frag phys slot

    for (int jt = 0; jt < KSEG / 256; ++jt) {
        const int colBase = codeBase + jt * 256;
        f32x4 acc[4][8];
        #pragma unroll
        for (int mt = 0; mt < 4; ++mt)
            #pragma unroll
            for (int nt = 0; nt < 8; ++nt) {
                f32x4 z = {0.0f, 0.0f, 0.0f, 0.0f};
                acc[mt][nt] = z;
            }

        for (int kc = 0; kc < 256; kc += 32) {
            __syncthreads();
            #pragma unroll
            for (int j = 0; j < 4; ++j) {   // A: 128 rows
                int rr = (j * 4 + w) * 8 + l8;
                const char* gA = (const char*)(Ap + (size_t)(rowBase + rr) * 512 + kc + goff);
                load_lds16(gA, (char*)As + ((j * 4 + w) << 10));
            }
            #pragma unroll
            for (int j = 0; j < 8; ++j) {   // B: 256 rows
                int rr = (j * 4 + w) * 8 + l8;
                const char* gB = (const char*)(Bp + (size_t)(colBase + rr) * 512 + kc + goff);
                load_lds16(gB, (char*)Bs + ((j * 4 + w) << 10));
            }
            __syncthreads();

            f16x8 ah[4];
            #pragma unroll
            for (int mt = 0; mt < 4; ++mt) {
                int r = wy * 64 + mt * 16 + t16;
                ah[mt] = *(const f16x8*)((const char*)As + r * 128 + (sA << 4));
            }
            {   // hh
                f16x8 bh[8];
                #pragma unroll
                for (int nt = 0; nt < 8; ++nt) {
                    int r = wx * 128 + nt * 16 + t16;
                    bh[nt] = *(const f16x8*)((const char*)Bs + r * 128 + (sA << 4));
                }
                #pragma unroll
                for (int mt = 0; mt < 4; ++mt)
                    #pragma unroll
                    for (int nt = 0; nt < 8; ++nt)
                        acc[mt][nt] = __builtin_amdgcn_mfma_f32_16x16x32_f16(ah[mt], bh[nt], acc[mt][nt], 0, 0, 0);
            }
            {   // hl
                f16x8 bl[8];
                #pragma unroll
                for (int nt = 0; nt < 8; ++nt) {
                    int r = wx * 128 + nt * 16 + t16;
                    bl[nt] = *(const f16x8*)((const char*)Bs + r * 128 + (sL << 4));
                }
                #pragma unroll
                for (int mt = 0; mt < 4; ++mt)
                    #pragma unroll
                    for (int nt = 0; nt < 8; ++nt)
                        acc[mt][nt] = __builtin_amdgcn_mfma_f32_16x16x32_f16(ah[mt], bl[nt], acc[mt][nt], 0, 0, 0);
            }
            {   // lh: fresh al, re-read bh (keeps live-set ~2 fragment sets)
                f16x8 al[4], bh2[8];
                #pragma unroll
                for (int mt = 0; mt < 4; ++mt) {
                    int r = wy * 64 + mt * 16 + t16;
                    al[mt] = *(const f16x8*)((const char*)As + r * 128 + (sL << 4));
                }
                #pragma unroll
                for (int nt = 0; nt < 8; ++nt) {
                    int r = wx * 128 + nt * 16 + t16;
                    bh2[nt] = *(const f16x8*)((const char*)Bs + r * 128 + (sA << 4));
                }
                #pragma unroll
                for (int mt = 0; mt < 4; ++mt)
                    #pragma unroll
                    for (int nt = 0; nt < 8; ++nt)
                        acc[mt][nt] = __builtin_amdgcn_mfma_f32_16x16x32_f16(al[mt], bh2[nt], acc[mt][nt], 0, 0, 0);
            }
        }

        // epilogue: dist = nx + ne - 2*dot; cols ascending -> first-min-wins
        #pragma unroll
        for (int nt = 0; nt < 8; ++nt) {
            int col = colBase + wx * 128 + nt * 16 + t16;
            float nec = ne[col];
            #pragma unroll
            for (int mt = 0; mt < 4; ++mt)
                #pragma unroll
                for (int r = 0; r < 4; ++r) {
                    float d = nxr[mt * 4 + r] + nec - 2.0f * acc[mt][nt][r];
                    if (d < minval[mt * 4 + r]) { minval[mt * 4 + r] = d; minidx[mt * 4 + r] = col; }
                }
        }
    }

    // reduce over the 16 col-lanes (lane bits 0-3), tie -> smaller index
    #pragma unroll
    for (int i = 0; i < 16; ++i) {
        float v = minval[i]; int ix = minidx[i];
        #pragma unroll
        for (int m = 1; m < 16; m <<= 1) {
            float ov = __shfl_xor(v, m, 64);
            int   oi = __shfl_xor(ix, m, 64);
            if (ov < v || (ov == v && oi < ix)) { v = ov; ix = oi; }
        }
        minval[i] = v; minidx[i] = ix;
    }
    __syncthreads();
    if (t16 == 0) {
        #pragma unroll
        for (int mt = 0; mt < 4; ++mt)
            #pragma unroll
            for (int r = 0; r < 4; ++r) {
                int rl = wy * 64 + mt * 16 + quad * 4 + r;
                sval2[wx][rl] = minval[mt * 4 + r];
                sidx2[wx][rl] = minidx[mt * 4 + r];
            }
    }
    __syncthreads();
    if (tid < 128) {
        float v0 = sval2[0][tid]; int i0 = sidx2[0][tid];
        float v1 = sval2[1][tid]; int i1 = sidx2[1][tid];
        if (v1 < v0 || (v1 == v0 && i1 < i0)) { v0 = v1; i0 = i1; }
        val_part[ks * ND_ROWS + rowBase + tid] = v0;
        idx_part[ks * ND_ROWS + rowBase + tid] = i0;
    }
}

// merge splits, gather codebook row, write quantized_sg + float index,
// histogram atomic + per-block SSE partials (no same-address float atomics).
__global__ __launch_bounds__(256) void finalize_kernel(
    const float* __restrict__ x, const float* __restrict__ emb,
    const float* __restrict__ val_part, const int* __restrict__ idx_part,
    float* __restrict__ out_q, float* __restrict__ out_idx,
    int* __restrict__ counts, float* __restrict__ parts) {
    __shared__ float rde[4], rdq[4];
    int wv   = threadIdx.x >> 6;
    int row  = (blockIdx.x << 2) + wv;
    int lane = threadIdx.x & 63;

    float bv = val_part[row];
    int   bi = idx_part[row];
    #pragma unroll
    for (int p = 1; p < NSPLIT; ++p) {
        float v  = val_part[p * ND_ROWS + row];
        int   i2 = idx_part[p * ND_ROWS + row];
        if (v < bv || (v == bv && i2 < bi)) { bv = v; bi = i2; }
    }

    float4 xv = ((const float4*)(x   + (size_t)row * DDIM))[lane];
    float4 ev = ((const float4*)(emb + (size_t)bi  * DDIM))[lane];
    float4 q;
    q.x = xv.x + (ev.x - xv.x);
    q.y = xv.y + (ev.y - xv.y);
    q.z = xv.z + (ev.z - xv.z);
    q.w = xv.w + (ev.w - xv.w);
    ((float4*)(out_q + (size_t)row * DDIM))[lane] = q;

    float de = (ev.x - xv.x) * (ev.x - xv.x) + (ev.y - xv.y) * (ev.y - xv.y)
             + (ev.z - xv.z) * (ev.z - xv.z) + (ev.w - xv.w) * (ev.w - xv.w);
    float dq = (q.x - ev.x) * (q.x - ev.x) + (q.y - ev.y) * (q.y - ev.y)
             + (q.z - ev.z) * (q.z - ev.z) + (q.w - ev.w) * (q.w - ev.w);
    #pragma unroll
    for (int m = 32; m; m >>= 1) {
        de += __shfl_xor(de, m, 64);
        dq += __shfl_xor(dq, m, 64);
    }
    if (lane == 0) {
        out_idx[row] = (float)bi;
        atomicAdd(&counts[bi], 1);
        rde[wv] = de; rdq[wv] = dq;
    }
    __syncthreads();
    if (threadIdx.x == 0) {
        parts[blockIdx.x]        = rde[0] + rde[1] + rde[2] + rde[3];
        parts[4096 + blockIdx.x] = rdq[0] + rdq[1] + rdq[2] + rdq[3];
    }
}

__global__ __launch_bounds__(256) void scalars_kernel(
    const int* __restrict__ counts, const float* __restrict__ parts,
    float* __restrict__ out_loss, float* __restrict__ out_perp) {
    __shared__ float red[256], rde[256], rdq[256];
    float local = 0.0f, de = 0.0f, dq = 0.0f;
    for (int k = threadIdx.x; k < KCODES; k += 256) {
        float p = (float)counts[k] * (1.0f / (float)ND_ROWS);
        local += p * logf(p + 1e-10f);
    }
    for (int k = threadIdx.x; k < 4096; k += 256) {
        de += parts[k];
        dq += parts[4096 + k];
    }
    red[threadIdx.x] = local; rde[threadIdx.x] = de; rdq[threadIdx.x] = dq;
    __syncthreads();
    for (int s = 128; s; s >>= 1) {
        if (threadIdx.x < s) {
            red[threadIdx.x] += red[threadIdx.x + s];
            rde[threadIdx.x] += rde[threadIdx.x + s];
            rdq[threadIdx.x] += rdq[threadIdx.x + s];
        }
        __syncthreads();
    }
    if (threadIdx.x == 0) {
        *out_perp = expf(-red[0]);
        float invn = 1.0f / (float)(ND_ROWS * DDIM);
        *out_loss = rdq[0] * invn + 0.25f * (rde[0] * invn);
    }
}

extern "C" void kernel_launch(void* const* d_in, const int* in_sizes, int n_in,
                              void* d_out, int out_size, void* d_ws, size_t ws_size,
                              hipStream_t stream) {
    const float* x   = (const float*)d_in[0];
    const float* emb = (const float*)d_in[1];

    float* ws       = (float*)d_ws;
    float* ne       = ws;
    float* nx       = ws + 8192;
    float* val_part = ws + 24576;
    int*   idx_part = (int*)(ws + 155648);
    int*   counts   = (int*)(ws + 286720);
    float* parts    = ws + 294912;
    _Float16* Ap    = (_Float16*)(ws + 303104);        // 16B-aligned
    _Float16* Bp    = Ap + (size_t)ND_ROWS * 512;

    float* out_q    = (float*)d_out;
    float* out_idx  = out_q + (size_t)ND_ROWS * DDIM;
    float* out_loss = out_idx + ND_ROWS;
    float* out_perp = out_loss + 1;

    hipMemsetAsync(counts, 0, KCODES * sizeof(int), stream);

    prep_kernel<<<(KCODES + ND_ROWS) / 4, 256, 0, stream>>>(x, emb, Ap, Bp, nx, ne);
    argmin_mfma<<<(ND_ROWS / 128) * NSPLIT, 256, 0, stream>>>(Ap, Bp, nx, ne,
                                                              val_part, idx_part);
    finalize_kernel<<<ND_ROWS / 4, 256, 0, stream>>>(x, emb, val_part, idx_part,
                                                     out_q, out_idx, counts, parts);
    scalars_kernel<<<1, 256, 0, stream>>>(counts, parts, out_loss, out_perp);
}